// Round 2
// 72.272 us; speedup vs baseline: 1.0241x; 1.0241x over previous
//
#include <hip/hip_runtime.h>
#include <math.h>

// Problem constants (fixed by setup_inputs: N=1024, H=W=256, B=64).
#define HCONST 256
#define WCONST 256
#define ROWS   16                 // rows per block (stripe) -- was 32
#define TILES  (HCONST / ROWS)    // 16 stripes per batch image
#define CHUNK  64                 // gaussians processed per LDS refill

// ---------------------------------------------------------------------------
// v2 (resubmit; round-1 bench died on container acquisition, not the kernel):
// same LDS-broadcast formulation, restructured for latency hiding.
//
// g = fx(x)*fy(y) separable & positive -> grid max = max(fx)*max(fy) at the
// grid point nearest mu (step 1/255); 1/(2*pi*sx*sy) cancels in g/max(g).
// With ax=1/(2 sx^2), cx=ax*dxmin^2 (same for y):
//   g_norm[n,y,x] = pred[n] * exp(cx - ax*dx^2) * exp(cy - ay*dy^2)
//
// Changes vs v1 (74.0 us measured, fused modeled 6-8 us, latency-bound at
// 2 waves/SIMD):
//  - ROWS 32->16: grid 512->1024 blocks = 4 blocks/CU = 4 waves/SIMD.
//    LDS ~10.3 KB, VGPR ~70 -> __launch_bounds__(256,4) is satisfiable.
//  - y-params {muy, ay, cy, pred} computed ONCE per gaussian (t<cc) instead
//    of per (gaussian,row): removes 31/32 of the nodes[] gathers and the
//    rcp/round from the fy loop's dependent chain.
//  - batch_list scan via int4 (one vector load per thread at N=1024).
//  - inner g-loop manually unrolled x2 for ILP across two gaussians.
// Output written exactly once -> no pre-zero needed.
// ---------------------------------------------------------------------------
__global__ __launch_bounds__(256, 4) void fused_kernel(
    const float* __restrict__ pred,
    const float* __restrict__ nodes,      // (N,4): mux, muy, sx, sy
    const int*   __restrict__ batch_list,
    int N,
    float* __restrict__ out)
{
    const int b  = blockIdx.x / TILES;
    const int ty = blockIdx.x % TILES;
    const int y0 = ty * ROWS;
    const int t  = threadIdx.x;
    const int xi   = t & 127;        // column pair index: x = 2*xi, 2*xi+1
    const int half = t >> 7;         // 0: rows y0..y0+7, 1: rows y0+8..y0+15

    __shared__ int    s_idx[1024];
    __shared__ int    s_cnt;
    __shared__ float4 s_px[CHUNK];          // {mux, ax, cx, -}
    __shared__ float4 s_py[CHUNK];          // {muy, ay, cy, pred}
    __shared__ float  s_fy[CHUNK][ROWS];    // pred * fy, stripe rows

    if (t == 0) s_cnt = 0;
    __syncthreads();

    // --- phase 1: compact this batch's gaussian ids (vectorized scan) ---
    {
        const int4* bl4 = (const int4*)batch_list;
        for (int q = t; q < (N >> 2); q += 256) {
            const int4 v = bl4[q];
            if (v.x == b) s_idx[atomicAdd(&s_cnt, 1)] = 4 * q;
            if (v.y == b) s_idx[atomicAdd(&s_cnt, 1)] = 4 * q + 1;
            if (v.z == b) s_idx[atomicAdd(&s_cnt, 1)] = 4 * q + 2;
            if (v.w == b) s_idx[atomicAdd(&s_cnt, 1)] = 4 * q + 3;
        }
        for (int n = (N & ~3) + t; n < N; n += 256)       // no-op for N=1024
            if (batch_list[n] == b) s_idx[atomicAdd(&s_cnt, 1)] = n;
    }
    __syncthreads();
    const int cnt = s_cnt;

    const float step = 1.0f / 255.0f;
    const float x0s = (2 * xi)     * step;
    const float x1s = (2 * xi + 1) * step;

    float2 acc[8];
#pragma unroll
    for (int r = 0; r < 8; ++r) acc[r] = make_float2(0.0f, 0.0f);

    for (int c0 = 0; c0 < cnt; c0 += CHUNK) {
        const int cc = min(CHUNK, cnt - c0);

        // --- phase 2a: per-gaussian x- and y-params, once per gaussian ---
        if (t < cc) {
            const int n = s_idx[c0 + t];
            const float4 nd = ((const float4*)nodes)[n];
            const float pr = pred[n];
            const float ax = 1.0f / (2.0f * nd.z * nd.z);
            const float ay = 1.0f / (2.0f * nd.w * nd.w);
            float nix = fminf(fmaxf(roundf(nd.x * 255.0f), 0.0f), 255.0f);
            float niy = fminf(fmaxf(roundf(nd.y * 255.0f), 0.0f), 255.0f);
            const float dxm = nix * step - nd.x;
            const float dym = niy * step - nd.y;
            s_px[t] = make_float4(nd.x, ax, ax * dxm * dxm, 0.0f);
            s_py[t] = make_float4(nd.y, ay, ay * dym * dym, pr);
        }
        __syncthreads();

        // --- phase 2b: fy for the stripe's 16 rows (pred folded in) ---
        for (int it = t; it < cc * ROWS; it += 256) {
            const int g  = it >> 4;
            const int yy = it & 15;
            const float4 py = s_py[g];                    // LDS, not global
            const float dy = (y0 + yy) * step - py.x;
            s_fy[g][yy] = py.w * __expf(py.z - py.y * dy * dy);
        }
        __syncthreads();

        // --- phase 3: accumulate, two gaussians per iteration ---
        int g = 0;
        for (; g + 2 <= cc; g += 2) {
            const float4 pa = s_px[g];                    // broadcast
            const float4 pb = s_px[g + 1];
            const float dxa0 = x0s - pa.x, dxa1 = x1s - pa.x;
            const float dxb0 = x0s - pb.x, dxb1 = x1s - pb.x;
            const float ea0 = __expf(pa.z - pa.y * dxa0 * dxa0);
            const float ea1 = __expf(pa.z - pa.y * dxa1 * dxa1);
            const float eb0 = __expf(pb.z - pb.y * dxb0 * dxb0);
            const float eb1 = __expf(pb.z - pb.y * dxb1 * dxb1);
            const float4* fa4 = (const float4*)&s_fy[g][half * 8];
            const float4* fb4 = (const float4*)&s_fy[g + 1][half * 8];
#pragma unroll
            for (int k = 0; k < 2; ++k) {
                const float4 fa = fa4[k];                 // broadcast b128
                const float4 fb = fb4[k];
                acc[k*4+0].x = fmaf(fa.x, ea0, acc[k*4+0].x);
                acc[k*4+0].y = fmaf(fa.x, ea1, acc[k*4+0].y);
                acc[k*4+1].x = fmaf(fa.y, ea0, acc[k*4+1].x);
                acc[k*4+1].y = fmaf(fa.y, ea1, acc[k*4+1].y);
                acc[k*4+2].x = fmaf(fa.z, ea0, acc[k*4+2].x);
                acc[k*4+2].y = fmaf(fa.z, ea1, acc[k*4+2].y);
                acc[k*4+3].x = fmaf(fa.w, ea0, acc[k*4+3].x);
                acc[k*4+3].y = fmaf(fa.w, ea1, acc[k*4+3].y);
                acc[k*4+0].x = fmaf(fb.x, eb0, acc[k*4+0].x);
                acc[k*4+0].y = fmaf(fb.x, eb1, acc[k*4+0].y);
                acc[k*4+1].x = fmaf(fb.y, eb0, acc[k*4+1].x);
                acc[k*4+1].y = fmaf(fb.y, eb1, acc[k*4+1].y);
                acc[k*4+2].x = fmaf(fb.z, eb0, acc[k*4+2].x);
                acc[k*4+2].y = fmaf(fb.z, eb1, acc[k*4+2].y);
                acc[k*4+3].x = fmaf(fb.w, eb0, acc[k*4+3].x);
                acc[k*4+3].y = fmaf(fb.w, eb1, acc[k*4+3].y);
            }
        }
        if (g < cc) {                                     // odd-count tail
            const float4 pa = s_px[g];
            const float dx0 = x0s - pa.x, dx1 = x1s - pa.x;
            const float e0 = __expf(pa.z - pa.y * dx0 * dx0);
            const float e1 = __expf(pa.z - pa.y * dx1 * dx1);
            const float4* fa4 = (const float4*)&s_fy[g][half * 8];
#pragma unroll
            for (int k = 0; k < 2; ++k) {
                const float4 f = fa4[k];
                acc[k*4+0].x = fmaf(f.x, e0, acc[k*4+0].x);
                acc[k*4+0].y = fmaf(f.x, e1, acc[k*4+0].y);
                acc[k*4+1].x = fmaf(f.y, e0, acc[k*4+1].x);
                acc[k*4+1].y = fmaf(f.y, e1, acc[k*4+1].y);
                acc[k*4+2].x = fmaf(f.z, e0, acc[k*4+2].x);
                acc[k*4+2].y = fmaf(f.z, e1, acc[k*4+2].y);
                acc[k*4+3].x = fmaf(f.w, e0, acc[k*4+3].x);
                acc[k*4+3].y = fmaf(f.w, e1, acc[k*4+3].y);
            }
        }
        __syncthreads();   // before next chunk overwrites s_px/s_py/s_fy
    }

    // --- store: float2 per row, coalesced across xi ---
    float* o = out + ((size_t)b * HCONST + y0 + half * 8) * WCONST + 2 * xi;
#pragma unroll
    for (int r = 0; r < 8; ++r)
        ((float2*)(o + (size_t)r * WCONST))[0] = acc[r];
}

// ---------------------------------------------------------------------------
extern "C" void kernel_launch(void* const* d_in, const int* in_sizes, int n_in,
                              void* d_out, int out_size, void* d_ws, size_t ws_size,
                              hipStream_t stream) {
    const float* pred       = (const float*)d_in[0];
    const float* nodes      = (const float*)d_in[1];
    const int*   batch_list = (const int*)d_in[2];

    const int N = in_sizes[0];                    // 1024
    const int B = out_size / (HCONST * WCONST);   // 64

    float* out = (float*)d_out;

    fused_kernel<<<B * TILES, 256, 0, stream>>>(pred, nodes, batch_list, N, out);
}